// Round 2
// baseline (1194.719 us; speedup 1.0000x reference)
//
#include <hip/hip_runtime.h>
#include <cstdint>

#define NNZ   100000
#define CBINS 16
#define HD    1024
#define WD    1024
#define CIN   128
#define CH    128
#define QMAX  (NNZ * (CBINS - 1))

// ============================ threefry2x32 (JAX) ============================
struct Key { uint32_t a, b; };

__device__ __forceinline__ uint32_t rotl32(uint32_t v, int r) {
  return (v << r) | (v >> (32 - r));
}

__device__ __forceinline__ void tf_block(uint32_t k0, uint32_t k1,
                                         uint32_t x0, uint32_t x1,
                                         uint32_t& o0, uint32_t& o1) {
  uint32_t ks2 = k0 ^ k1 ^ 0x1BD11BDAu;
  x0 += k0; x1 += k1;
#define TF_RND(r) { x0 += x1; x1 = rotl32(x1, r); x1 ^= x0; }
  TF_RND(13) TF_RND(15) TF_RND(26) TF_RND(6)
  x0 += k1;  x1 += ks2 + 1u;
  TF_RND(17) TF_RND(29) TF_RND(16) TF_RND(24)
  x0 += ks2; x1 += k0 + 2u;
  TF_RND(13) TF_RND(15) TF_RND(26) TF_RND(6)
  x0 += k0;  x1 += k1 + 3u;
  TF_RND(17) TF_RND(29) TF_RND(16) TF_RND(24)
  x0 += k1;  x1 += ks2 + 4u;
  TF_RND(13) TF_RND(15) TF_RND(26) TF_RND(6)
  x0 += ks2; x1 += k0 + 5u;
#undef TF_RND
  o0 = x0; o1 = x1;
}

// partitionable-mode split: subkey[i] = block(key, (0, i))
__device__ __forceinline__ Key tf_key(Key k, uint32_t chi, uint32_t clo) {
  Key r; tf_block(k.a, k.b, chi, clo, r.a, r.b); return r;
}

// partitionable-mode scalar random_bits (32-bit): xor of the two halves of
// block(key, (0,0))
__device__ __forceinline__ uint32_t random_bits32(Key k) {
  uint32_t a, b; tf_block(k.a, k.b, 0u, 0u, a, b); return a ^ b;
}

// ============================ JAX float samplers ============================
__device__ __forceinline__ float bits_to_u01(uint32_t bits) {
  // bitcast((bits >> 9) | 0x3F800000) - 1.0  in [0, 1)
  uint32_t fb = (bits >> 9) | 0x3F800000u;
  return __uint_as_float(fb) - 1.0f;
}

// XLA ErfInv32 (Giles 2012), mul/add NOT contracted (XLA emits separate ops)
__device__ float erfinv32(float x) {
#pragma clang fp contract(off)
  float w = -log1pf(-(x * x));
  float p;
  if (w < 5.0f) {
    w = w - 2.5f;
    p = 2.81022636e-08f;
    p = 3.43273939e-07f  + p * w;
    p = -3.5233877e-06f  + p * w;
    p = -4.39150654e-06f + p * w;
    p = 0.00021858087f   + p * w;
    p = -0.00125372503f  + p * w;
    p = -0.00417768164f  + p * w;
    p = 0.246640727f     + p * w;
    p = 1.50140941f      + p * w;
  } else {
    w = sqrtf(w) - 3.0f;
    p = -0.000200214257f;
    p = 0.000100950558f  + p * w;
    p = 0.00134934322f   + p * w;
    p = -0.00367342844f  + p * w;
    p = 0.00573950773f   + p * w;
    p = -0.0076224613f   + p * w;
    p = 0.00943887047f   + p * w;
    p = 1.00167406f      + p * w;
    p = 2.83297682f      + p * w;
  }
  return p * x;
}

__device__ __forceinline__ float uniform01(Key k) {  // uniform(key,(),f32,0,1)
  return bits_to_u01(random_bits32(k));              // *1 + 0, max(0,u) = u
}

__device__ __forceinline__ float normal_f32(Key k) { // jax.random.normal scalar
#pragma clang fp contract(off)
  const float LO = -0x1.fffffep-1f;  // nextafter(-1, 0)
  float f = bits_to_u01(random_bits32(k));
  float u = f * 2.0f + LO;           // (hi - lo) rounds to exactly 2.0f
  u = fmaxf(LO, u);
  return 1.4142135623730951f * erfinv32(u);
}

// _gamma_one(key, alpha, log_space=True) — Marsaglia–Tsang, JAX trace order
__device__ float loggamma_one(Key key, float alpha_orig) {
#pragma clang fp contract(off)
  bool boost = (alpha_orig >= 1.0f);
  float alpha = boost ? alpha_orig : (alpha_orig + 1.0f);
  const float OT = 0.3333333333333333f;  // f32(1/3)
  float d = alpha - OT;
  float c = OT / sqrtf(d);

  Key knext = tf_key(key, 0u, 0u);       // key, subkey = split(key)
  Key ksub  = tf_key(key, 0u, 1u);
  float u_boost = uniform01(ksub);

  float X = 0.0f, V = 1.0f, U = 2.0f;    // initial state passes cond
  while (true) {
    bool c1 = U >= (1.0f - 0.0331f * (X * X));
    bool c2 = logf(U) >= (X * 0.5f + d * ((1.0f - V) + logf(V)));
    if (!(c1 && c2)) break;
    // key, x_key, U_key = split(key, 3)
    Key kcur = knext;
    knext    = tf_key(kcur, 0u, 0u);
    Key xk   = tf_key(kcur, 0u, 1u);
    Key Uk   = tf_key(kcur, 0u, 2u);
    float x = 0.0f, v = -1.0f;
    while (v <= 0.0f) {                  // while v <= 0: redraw normal
      Key nxk = tf_key(xk, 0u, 0u);
      Key sk  = tf_key(xk, 0u, 1u);
      xk = nxk;
      x = normal_f32(sk);
      v = 1.0f + x * c;
    }
    X = x * x;
    V = (v * v) * v;
    U = uniform01(Uk);
  }
  float log_samples = logf(d) + logf(V);
  float log_boost = 0.0f;
  if (!boost && u_boost != 0.0f)
    log_boost = logf(u_boost) * (1.0f / alpha_orig);
  return log_samples + log_boost;
}

__device__ float beta_sample(Key ka, Key kb, uint32_t q, float a, float b) {
#pragma clang fp contract(off)
  Key ga = tf_key(ka, 0u, q);            // per-element gamma subkeys
  Key gb = tf_key(kb, 0u, q);
  float la = loggamma_one(ga, a);
  float lb = loggamma_one(gb, b);
  float lm = fmaxf(la, lb);
  float ea = expf(la - lm);
  float eb = expf(lb - lm);
  return ea / (ea + eb);
}

// ============================ pipeline kernels ============================

// Exact replica of jax.lax.associative_scan's add association for n=16.
// (jnp.cumsum lowers to associative_scan on GPU — a recursive odd/even tree,
// NOT a sequential sum; the rounding difference can flip `cdf > 0.95`.)
__device__ __forceinline__ void ascan16(const float* a, float* out) {
  float r[8], r2[4], r3[2];
#pragma unroll
  for (int i = 0; i < 8; ++i) r[i] = a[2 * i] + a[2 * i + 1];
#pragma unroll
  for (int i = 0; i < 4; ++i) r2[i] = r[2 * i] + r[2 * i + 1];
  r3[0] = r2[0] + r2[1];
  r3[1] = r2[2] + r2[3];
  float r4 = r3[0] + r3[1];
  float s3[2] = {r3[0], r4};
  float s2[4] = {r2[0], s3[0], s3[0] + r2[2], s3[1]};
  float sr[8] = {r[0],          s2[0],
                 s2[0] + r[2],  s2[1],
                 s2[1] + r[4],  s2[2],
                 s2[2] + r[6],  s2[3]};
  out[0] = a[0];
#pragma unroll
  for (int i = 0; i < 8; ++i) out[2 * i + 1] = sr[i];
#pragma unroll
  for (int i = 0; i < 7; ++i) out[2 * i + 2] = sr[i] + a[2 * i + 2];
}

// counts: softmax->cdf(tree assoc)->argmax of (16-k)*over ; also flat addrs
__global__ __launch_bounds__(256)
void counts_kernel(const float* __restrict__ occ_values,
                   const int* __restrict__ occ_idx,
                   int* __restrict__ counts,
                   int* __restrict__ flatall) {
  int i = blockIdx.x * 256 + threadIdx.x;
  if (i >= NNZ) return;
  const float4* vp = (const float4*)(occ_values + (size_t)i * CBINS);
  float4 q0 = vp[0], q1 = vp[1], q2 = vp[2], q3 = vp[3];
  float v[16] = {q0.x,q0.y,q0.z,q0.w, q1.x,q1.y,q1.z,q1.w,
                 q2.x,q2.y,q2.z,q2.w, q3.x,q3.y,q3.z,q3.w};
  float m = v[0];
#pragma unroll
  for (int k = 1; k < 16; ++k) m = fmaxf(m, v[k]);
  float e[16];
#pragma unroll
  for (int k = 0; k < 16; ++k) e[k] = expf(v[k] - m);
  float s = 0.0f;
#pragma unroll
  for (int k = 0; k < 16; ++k) s += e[k];
  float p[16], cdf[16];
#pragma unroll
  for (int k = 0; k < 16; ++k) p[k] = e[k] / s;
  ascan16(p, cdf);
  int cnt = 0; bool found = false;
#pragma unroll
  for (int k = 0; k < 16; ++k) {
    if (!found && cdf[k] > 0.95f) { found = true; cnt = k; }
  }
  counts[i] = found ? cnt : 0;
  int b_ = occ_idx[i], i_ = occ_idx[NNZ + i], j_ = occ_idx[2 * NNZ + i];
  flatall[i] = (b_ * HD + i_) * WD + j_;
}

// inclusive scan: per-block scan + block sums
#define SCAN_B 1024
__global__ __launch_bounds__(SCAN_B)
void scan_block_kernel(const int* __restrict__ counts, int* __restrict__ cum,
                       int* __restrict__ bsums) {
  __shared__ int sh[SCAN_B];
  int t = threadIdx.x;
  int i = blockIdx.x * SCAN_B + t;
  sh[t] = (i < NNZ) ? counts[i] : 0;
  __syncthreads();
  for (int off = 1; off < SCAN_B; off <<= 1) {
    int add = (t >= off) ? sh[t - off] : 0;
    __syncthreads();
    sh[t] += add;
    __syncthreads();
  }
  if (i < NNZ) cum[i] = sh[t];
  if (t == SCAN_B - 1) bsums[blockIdx.x] = sh[t];
}

__global__ void scan_sums_kernel(int* bsums, int nblocks) {  // 1 block of 128
  __shared__ int sh[128];
  int t = threadIdx.x;
  sh[t] = (t < nblocks) ? bsums[t] : 0;
  __syncthreads();
  for (int off = 1; off < 128; off <<= 1) {
    int add = (t >= off) ? sh[t - off] : 0;
    __syncthreads();
    sh[t] += add;
    __syncthreads();
  }
  if (t < nblocks) bsums[t] = sh[t];
}

__global__ __launch_bounds__(SCAN_B)
void scan_add_kernel(int* cum, const int* __restrict__ bsums) {
  int b = blockIdx.x;
  if (b == 0) return;
  int i = b * SCAN_B + threadIdx.x;
  if (i < NNZ) cum[i] += bsums[b - 1];
}

// neighbor lookup: flatall is strictly increasing (sorted per batch, batch-major)
__device__ __forceinline__ int find_site(const int* __restrict__ flatall, int tval) {
  int lo = 0, hi = NNZ;
  while (lo < hi) {
    int mid = (lo + hi) >> 1;
    if (flatall[mid] < tval) lo = mid + 1; else hi = mid;
  }
  return (lo < NNZ && flatall[lo] == tval) ? lo : -1;
}

// SubMConv2d(128->128, 3x3) + ReLU + (128->4) head. Gathered GEMM:
// [64 sites x 1152] @ [1152 x 128], K-chunked by 32 through LDS.
#define TSITES 64
#define BKK    32
__global__ __launch_bounds__(256)
void conv_head_kernel(const int* __restrict__ occ_idx,
                      const int* __restrict__ flatall,
                      const float* __restrict__ pv,
                      const float* __restrict__ w1,
                      const float* __restrict__ b1,
                      const float* __restrict__ w2,
                      const float* __restrict__ b2,
                      float* __restrict__ logp) {
  __shared__ int nidx[TSITES * 9];
  __shared__ union {
    struct { float A[TSITES * BKK]; float Wt[BKK * CH]; } st;  // 24 KB
    float Hh[TSITES * 129];                                    // 33 KB (pad 129)
  } u;

  int base = blockIdx.x * TSITES;
  int t = threadIdx.x;
  for (int idx = t; idx < TSITES * 9; idx += 256) {
    int s = idx / 9, n = idx - s * 9;
    int site = base + s;
    int r = -1;
    if (site < NNZ) {
      int b_ = occ_idx[site], i_ = occ_idx[NNZ + site], j_ = occ_idx[2 * NNZ + site];
      int ni = i_ + n / 3 - 1, nj = j_ + n % 3 - 1;
      if ((unsigned)ni < HD && (unsigned)nj < WD)
        r = find_site(flatall, (b_ * HD + ni) * WD + nj);
    }
    nidx[idx] = r;
  }

  int ts = t >> 5, to = t & 31;  // thread tile: 8 sites x 4 outputs
  float acc[8][4];
  {
    float4 bv = *(const float4*)(b1 + to * 4);
#pragma unroll
    for (int s8 = 0; s8 < 8; ++s8) {
      acc[s8][0] = bv.x; acc[s8][1] = bv.y; acc[s8][2] = bv.z; acc[s8][3] = bv.w;
    }
  }

  for (int k0 = 0; k0 < 9 * CIN; k0 += BKK) {
    __syncthreads();  // also covers nidx staging on first iteration
    for (int idx = t; idx < TSITES * BKK; idx += 256) {
      int s = idx >> 5, kk = idx & 31;
      int k = k0 + kk;
      int r = nidx[s * 9 + (k >> 7)];
      u.st.A[idx] = (r >= 0) ? pv[(size_t)r * CIN + (k & 127)] : 0.0f;
    }
    {
      const float4* srcw = (const float4*)(w1 + (size_t)k0 * CH);
      float4* dstw = (float4*)u.st.Wt;
      for (int idx = t; idx < BKK * CH / 4; idx += 256) dstw[idx] = srcw[idx];
    }
    __syncthreads();
#pragma unroll
    for (int kk = 0; kk < BKK; kk += 4) {
      float4 wq0 = ((const float4*)(u.st.Wt + (kk + 0) * CH))[to];
      float4 wq1 = ((const float4*)(u.st.Wt + (kk + 1) * CH))[to];
      float4 wq2 = ((const float4*)(u.st.Wt + (kk + 2) * CH))[to];
      float4 wq3 = ((const float4*)(u.st.Wt + (kk + 3) * CH))[to];
#pragma unroll
      for (int s8 = 0; s8 < 8; ++s8) {
        float4 a4 = *(const float4*)(u.st.A + (ts * 8 + s8) * BKK + kk);
        acc[s8][0] += a4.x * wq0.x; acc[s8][1] += a4.x * wq0.y;
        acc[s8][2] += a4.x * wq0.z; acc[s8][3] += a4.x * wq0.w;
        acc[s8][0] += a4.y * wq1.x; acc[s8][1] += a4.y * wq1.y;
        acc[s8][2] += a4.y * wq1.z; acc[s8][3] += a4.y * wq1.w;
        acc[s8][0] += a4.z * wq2.x; acc[s8][1] += a4.z * wq2.y;
        acc[s8][2] += a4.z * wq2.z; acc[s8][3] += a4.z * wq2.w;
        acc[s8][0] += a4.w * wq3.x; acc[s8][1] += a4.w * wq3.y;
        acc[s8][2] += a4.w * wq3.z; acc[s8][3] += a4.w * wq3.w;
      }
    }
  }
  __syncthreads();
#pragma unroll
  for (int s8 = 0; s8 < 8; ++s8) {
    int srow = ts * 8 + s8;
#pragma unroll
    for (int o = 0; o < 4; ++o)
      u.Hh[srow * 129 + to * 4 + o] = fmaxf(acc[s8][o], 0.0f);
  }
  __syncthreads();
  {
    int s = t & 63, j = t >> 6;
    float sum = 0.0f;
    for (int o = 0; o < CH; ++o) sum += u.Hh[s * 129 + o] * w2[o * 4 + j];
    sum += b2[j];
    int site = base + s;
    if (site < NNZ) logp[(size_t)site * 4 + j] = sum;
  }
}

// per-query: searchsorted(cum, q, 'right'), gather indices+params, Beta rsample
__global__ __launch_bounds__(256)
void query_kernel(const int* __restrict__ occ_idx,
                  const int* __restrict__ cum,
                  const float* __restrict__ logp,
                  float* __restrict__ out_idx,   // [QMAX, 3] as float
                  float* __restrict__ out_off) { // [QMAX, 2]
  int q = blockIdx.x * 256 + threadIdx.x;
  if (q >= QMAX) return;
  int total = cum[NNZ - 1];
  if (q >= total) {
    out_idx[(size_t)q * 3 + 0] = 0.0f;
    out_idx[(size_t)q * 3 + 1] = 0.0f;
    out_idx[(size_t)q * 3 + 2] = 0.0f;
    out_off[(size_t)q * 2 + 0] = 0.0f;
    out_off[(size_t)q * 2 + 1] = 0.0f;
    return;
  }
  int lo = 0, hi = NNZ;
  while (lo < hi) {
    int mid = (lo + hi) >> 1;
    if (cum[mid] <= q) lo = mid + 1; else hi = mid;
  }
  int src = (lo < NNZ - 1) ? lo : (NNZ - 1);
  out_idx[(size_t)q * 3 + 0] = (float)occ_idx[src];
  out_idx[(size_t)q * 3 + 1] = (float)occ_idx[NNZ + src];
  out_idx[(size_t)q * 3 + 2] = (float)occ_idx[2 * NNZ + src];

  float4 lp = *(const float4*)(logp + (size_t)src * 4);
  float p0 = expf(lp.x), p1 = expf(lp.y), p2 = expf(lp.z), p3 = expf(lp.w);

  // jax.random.key(42) -> (0,42); k1,k2 = split; key_a,key_b = split(k) in beta
  Key root{0u, 42u};
  Key k1  = tf_key(root, 0u, 0u);
  Key k2  = tf_key(root, 0u, 1u);
  Key kxa = tf_key(k1, 0u, 0u);
  Key kxb = tf_key(k1, 0u, 1u);
  Key kya = tf_key(k2, 0u, 0u);
  Key kyb = tf_key(k2, 0u, 1u);

  float x = beta_sample(kxa, kxb, (uint32_t)q, p0, p1);
  float y = beta_sample(kya, kyb, (uint32_t)q, p2, p3);
  out_off[(size_t)q * 2 + 0] = x;
  out_off[(size_t)q * 2 + 1] = y;
}

// ============================ launch ============================
extern "C" void kernel_launch(void* const* d_in, const int* in_sizes, int n_in,
                              void* d_out, int out_size, void* d_ws, size_t ws_size,
                              hipStream_t stream) {
  const float* occ_values = (const float*)d_in[0];
  const int*   occ_idx    = (const int*)d_in[1];
  const float* pv         = (const float*)d_in[2];
  const float* w1         = (const float*)d_in[3];
  const float* b1         = (const float*)d_in[4];
  const float* w2         = (const float*)d_in[5];
  const float* b2         = (const float*)d_in[6];

  char* ws = (char*)d_ws;
  auto alignup = [](size_t x) { return (x + 255) & ~(size_t)255; };
  size_t o = 0;
  int* counts  = (int*)(ws + o); o += alignup((size_t)NNZ * 4);
  int* cum     = (int*)(ws + o); o += alignup((size_t)NNZ * 4);
  int* flatall = (int*)(ws + o); o += alignup((size_t)NNZ * 4);
  int* bsums   = (int*)(ws + o); o += alignup(128 * 4);
  float* logp  = (float*)(ws + o); o += alignup((size_t)NNZ * 4 * sizeof(float));

  float* out_idx = (float*)d_out;
  float* out_off = out_idx + (size_t)QMAX * 3;

  counts_kernel<<<(NNZ + 255) / 256, 256, 0, stream>>>(occ_values, occ_idx,
                                                       counts, flatall);
  int nsb = (NNZ + SCAN_B - 1) / SCAN_B;  // 98
  scan_block_kernel<<<nsb, SCAN_B, 0, stream>>>(counts, cum, bsums);
  scan_sums_kernel<<<1, 128, 0, stream>>>(bsums, nsb);
  scan_add_kernel<<<nsb, SCAN_B, 0, stream>>>(cum, bsums);
  conv_head_kernel<<<(NNZ + TSITES - 1) / TSITES, 256, 0, stream>>>(
      occ_idx, flatall, pv, w1, b1, w2, b2, logp);
  query_kernel<<<(QMAX + 255) / 256, 256, 0, stream>>>(occ_idx, cum, logp,
                                                       out_idx, out_off);
}

// Round 3
// 790.231 us; speedup vs baseline: 1.5119x; 1.5119x over previous
//
#include <hip/hip_runtime.h>
#include <cstdint>

#define NNZ   100000
#define CBINS 16
#define HD    1024
#define WD    1024
#define CIN   128
#define CH    128
#define QMAX  (NNZ * (CBINS - 1))

// ============================ threefry2x32 (JAX) ============================
struct Key { uint32_t a, b; };

__device__ __forceinline__ uint32_t rotl32(uint32_t v, int r) {
  return (v << r) | (v >> (32 - r));
}

__device__ __forceinline__ void tf_block(uint32_t k0, uint32_t k1,
                                         uint32_t x0, uint32_t x1,
                                         uint32_t& o0, uint32_t& o1) {
  uint32_t ks2 = k0 ^ k1 ^ 0x1BD11BDAu;
  x0 += k0; x1 += k1;
#define TF_RND(r) { x0 += x1; x1 = rotl32(x1, r); x1 ^= x0; }
  TF_RND(13) TF_RND(15) TF_RND(26) TF_RND(6)
  x0 += k1;  x1 += ks2 + 1u;
  TF_RND(17) TF_RND(29) TF_RND(16) TF_RND(24)
  x0 += ks2; x1 += k0 + 2u;
  TF_RND(13) TF_RND(15) TF_RND(26) TF_RND(6)
  x0 += k0;  x1 += k1 + 3u;
  TF_RND(17) TF_RND(29) TF_RND(16) TF_RND(24)
  x0 += k1;  x1 += ks2 + 4u;
  TF_RND(13) TF_RND(15) TF_RND(26) TF_RND(6)
  x0 += ks2; x1 += k0 + 5u;
#undef TF_RND
  o0 = x0; o1 = x1;
}

// partitionable-mode split: subkey[i] = block(key, (0, i))
__device__ __forceinline__ Key tf_key(Key k, uint32_t chi, uint32_t clo) {
  Key r; tf_block(k.a, k.b, chi, clo, r.a, r.b); return r;
}

// partitionable-mode scalar random_bits: xor of halves of block(key,(0,0))
__device__ __forceinline__ uint32_t random_bits32(Key k) {
  uint32_t a, b; tf_block(k.a, k.b, 0u, 0u, a, b); return a ^ b;
}

// ============================ JAX float samplers ============================
__device__ __forceinline__ float bits_to_u01(uint32_t bits) {
  uint32_t fb = (bits >> 9) | 0x3F800000u;
  return __uint_as_float(fb) - 1.0f;
}

// XLA ErfInv32 (Giles 2012), mul/add NOT contracted
__device__ float erfinv32(float x) {
#pragma clang fp contract(off)
  float w = -log1pf(-(x * x));
  float p;
  if (w < 5.0f) {
    w = w - 2.5f;
    p = 2.81022636e-08f;
    p = 3.43273939e-07f  + p * w;
    p = -3.5233877e-06f  + p * w;
    p = -4.39150654e-06f + p * w;
    p = 0.00021858087f   + p * w;
    p = -0.00125372503f  + p * w;
    p = -0.00417768164f  + p * w;
    p = 0.246640727f     + p * w;
    p = 1.50140941f      + p * w;
  } else {
    w = sqrtf(w) - 3.0f;
    p = -0.000200214257f;
    p = 0.000100950558f  + p * w;
    p = 0.00134934322f   + p * w;
    p = -0.00367342844f  + p * w;
    p = 0.00573950773f   + p * w;
    p = -0.0076224613f   + p * w;
    p = 0.00943887047f   + p * w;
    p = 1.00167406f      + p * w;
    p = 2.83297682f      + p * w;
  }
  return p * x;
}

__device__ __forceinline__ float uniform01(Key k) {
  return bits_to_u01(random_bits32(k));
}

__device__ __forceinline__ float normal_f32(Key k) {
#pragma clang fp contract(off)
  const float LO = -0x1.fffffep-1f;  // nextafter(-1, 0)
  float f = bits_to_u01(random_bits32(k));
  float u = f * 2.0f + LO;
  u = fmaxf(LO, u);
  return 1.4142135623730951f * erfinv32(u);
}

// _gamma_one(key, alpha, log_space=True) — Marsaglia–Tsang, JAX trace order
__device__ float loggamma_one(Key key, float alpha_orig) {
#pragma clang fp contract(off)
  bool boost = (alpha_orig >= 1.0f);
  float alpha = boost ? alpha_orig : (alpha_orig + 1.0f);
  const float OT = 0.3333333333333333f;
  float d = alpha - OT;
  float c = OT / sqrtf(d);

  Key knext = tf_key(key, 0u, 0u);
  Key ksub  = tf_key(key, 0u, 1u);
  float u_boost = uniform01(ksub);

  float X = 0.0f, V = 1.0f, U = 2.0f;
  while (true) {
    bool c1 = U >= (1.0f - 0.0331f * (X * X));
    bool c2 = logf(U) >= (X * 0.5f + d * ((1.0f - V) + logf(V)));
    if (!(c1 && c2)) break;
    Key kcur = knext;
    knext    = tf_key(kcur, 0u, 0u);
    Key xk   = tf_key(kcur, 0u, 1u);
    Key Uk   = tf_key(kcur, 0u, 2u);
    float x = 0.0f, v = -1.0f;
    while (v <= 0.0f) {
      Key nxk = tf_key(xk, 0u, 0u);
      Key sk  = tf_key(xk, 0u, 1u);
      xk = nxk;
      x = normal_f32(sk);
      v = 1.0f + x * c;
    }
    X = x * x;
    V = (v * v) * v;
    U = uniform01(Uk);
  }
  float log_samples = logf(d) + logf(V);
  float log_boost = 0.0f;
  if (!boost && u_boost != 0.0f)
    log_boost = logf(u_boost) * (1.0f / alpha_orig);
  return log_samples + log_boost;
}

__device__ float beta_sample(Key ka, Key kb, uint32_t q, float a, float b) {
#pragma clang fp contract(off)
  Key ga = tf_key(ka, 0u, q);
  Key gb = tf_key(kb, 0u, q);
  float la = loggamma_one(ga, a);
  float lb = loggamma_one(gb, b);
  float lm = fmaxf(la, lb);
  float ea = expf(la - lm);
  float eb = expf(lb - lm);
  return ea / (ea + eb);
}

// ============================ pipeline kernels ============================

// Exact replica of jax.lax.associative_scan's add association for n=16.
__device__ __forceinline__ void ascan16(const float* a, float* out) {
  float r[8], r2[4], r3[2];
#pragma unroll
  for (int i = 0; i < 8; ++i) r[i] = a[2 * i] + a[2 * i + 1];
#pragma unroll
  for (int i = 0; i < 4; ++i) r2[i] = r[2 * i] + r[2 * i + 1];
  r3[0] = r2[0] + r2[1];
  r3[1] = r2[2] + r2[3];
  float r4 = r3[0] + r3[1];
  float s3[2] = {r3[0], r4};
  float s2[4] = {r2[0], s3[0], s3[0] + r2[2], s3[1]};
  float sr[8] = {r[0],          s2[0],
                 s2[0] + r[2],  s2[1],
                 s2[1] + r[4],  s2[2],
                 s2[2] + r[6],  s2[3]};
  out[0] = a[0];
#pragma unroll
  for (int i = 0; i < 8; ++i) out[2 * i + 1] = sr[i];
#pragma unroll
  for (int i = 0; i < 7; ++i) out[2 * i + 2] = sr[i] + a[2 * i + 2];
}

__global__ __launch_bounds__(256)
void counts_kernel(const float* __restrict__ occ_values,
                   const int* __restrict__ occ_idx,
                   int* __restrict__ counts,
                   int* __restrict__ flatall) {
  int i = blockIdx.x * 256 + threadIdx.x;
  if (i >= NNZ) return;
  const float4* vp = (const float4*)(occ_values + (size_t)i * CBINS);
  float4 q0 = vp[0], q1 = vp[1], q2 = vp[2], q3 = vp[3];
  float v[16] = {q0.x,q0.y,q0.z,q0.w, q1.x,q1.y,q1.z,q1.w,
                 q2.x,q2.y,q2.z,q2.w, q3.x,q3.y,q3.z,q3.w};
  float m = v[0];
#pragma unroll
  for (int k = 1; k < 16; ++k) m = fmaxf(m, v[k]);
  float e[16];
#pragma unroll
  for (int k = 0; k < 16; ++k) e[k] = expf(v[k] - m);
  float s = 0.0f;
#pragma unroll
  for (int k = 0; k < 16; ++k) s += e[k];
  float p[16], cdf[16];
#pragma unroll
  for (int k = 0; k < 16; ++k) p[k] = e[k] / s;
  ascan16(p, cdf);
  int cnt = 0; bool found = false;
#pragma unroll
  for (int k = 0; k < 16; ++k) {
    if (!found && cdf[k] > 0.95f) { found = true; cnt = k; }
  }
  counts[i] = found ? cnt : 0;
  int b_ = occ_idx[i], i_ = occ_idx[NNZ + i], j_ = occ_idx[2 * NNZ + i];
  flatall[i] = (b_ * HD + i_) * WD + j_;
}

#define SCAN_B 1024
__global__ __launch_bounds__(SCAN_B)
void scan_block_kernel(const int* __restrict__ counts, int* __restrict__ cum,
                       int* __restrict__ bsums) {
  __shared__ int sh[SCAN_B];
  int t = threadIdx.x;
  int i = blockIdx.x * SCAN_B + t;
  sh[t] = (i < NNZ) ? counts[i] : 0;
  __syncthreads();
  for (int off = 1; off < SCAN_B; off <<= 1) {
    int add = (t >= off) ? sh[t - off] : 0;
    __syncthreads();
    sh[t] += add;
    __syncthreads();
  }
  if (i < NNZ) cum[i] = sh[t];
  if (t == SCAN_B - 1) bsums[blockIdx.x] = sh[t];
}

__global__ void scan_sums_kernel(int* bsums, int nblocks) {
  __shared__ int sh[128];
  int t = threadIdx.x;
  sh[t] = (t < nblocks) ? bsums[t] : 0;
  __syncthreads();
  for (int off = 1; off < 128; off <<= 1) {
    int add = (t >= off) ? sh[t - off] : 0;
    __syncthreads();
    sh[t] += add;
    __syncthreads();
  }
  if (t < nblocks) bsums[t] = sh[t];
}

__global__ __launch_bounds__(SCAN_B)
void scan_add_kernel(int* cum, const int* __restrict__ bsums) {
  int b = blockIdx.x;
  if (b == 0) return;
  int i = b * SCAN_B + threadIdx.x;
  if (i < NNZ) cum[i] += bsums[b - 1];
}

__device__ __forceinline__ int find_site(const int* __restrict__ flatall, int tval) {
  int lo = 0, hi = NNZ;
  while (lo < hi) {
    int mid = (lo + hi) >> 1;
    if (flatall[mid] < tval) lo = mid + 1; else hi = mid;
  }
  return (lo < NNZ && flatall[lo] == tval) ? lo : -1;
}

// SubMConv2d(128->128, 3x3) + ReLU + (128->4) head. Gathered GEMM:
// [64 sites x 1152] @ [1152 x 128], K-chunked by 32 through LDS.
// A rows padded to 40 dwords (stride ≡ 8 mod 32 banks); thread's two
// half-wave rows are ADJACENT (site = s8*8+ts) so A reads are conflict-free.
// Head computed in registers + __shfl_xor butterfly (no Hh LDS buffer).
#define TSITES 64
#define BKK    32
#define APAD   40
__global__ __launch_bounds__(256, 5)
void conv_head_kernel(const int* __restrict__ occ_idx,
                      const int* __restrict__ flatall,
                      const float* __restrict__ pv,
                      const float* __restrict__ w1,
                      const float* __restrict__ b1,
                      const float* __restrict__ w2,
                      const float* __restrict__ b2,
                      float* __restrict__ logp) {
  __shared__ int nidx[TSITES * 9];          // 2.25 KB
  __shared__ float Ash[TSITES * APAD];      // 10.0 KB
  __shared__ float Wsh[BKK * CH];           // 16.0 KB

  int base = blockIdx.x * TSITES;
  int t = threadIdx.x;
  for (int idx = t; idx < TSITES * 9; idx += 256) {
    int s = idx / 9, n = idx - s * 9;
    int site = base + s;
    int r = -1;
    if (site < NNZ) {
      int b_ = occ_idx[site], i_ = occ_idx[NNZ + site], j_ = occ_idx[2 * NNZ + site];
      int ni = i_ + n / 3 - 1, nj = j_ + n % 3 - 1;
      if ((unsigned)ni < HD && (unsigned)nj < WD)
        r = find_site(flatall, (b_ * HD + ni) * WD + nj);
    }
    nidx[idx] = r;
  }

  int ts = t >> 5, to = t & 31;  // thread tile: 8 sites (s8*8+ts) x 4 outputs
  float acc[8][4];
  {
    float4 bv = *(const float4*)(b1 + to * 4);
#pragma unroll
    for (int s8 = 0; s8 < 8; ++s8) {
      acc[s8][0] = bv.x; acc[s8][1] = bv.y; acc[s8][2] = bv.z; acc[s8][3] = bv.w;
    }
  }

  for (int k0 = 0; k0 < 9 * CIN; k0 += BKK) {
    __syncthreads();  // also covers nidx staging on first iteration
    // stage A: 512 float4 gathers (2 per thread), rows padded to APAD
    {
      int tap = k0 >> 7, col0 = k0 & 127;
#pragma unroll
      for (int rep = 0; rep < 2; ++rep) {
        int idx = t + rep * 256;
        int s = idx >> 3, c = idx & 7;
        int r = nidx[s * 9 + tap];
        float4 val = make_float4(0.f, 0.f, 0.f, 0.f);
        if (r >= 0)
          val = *(const float4*)(pv + (size_t)r * CIN + col0 + 4 * c);
        *(float4*)(Ash + s * APAD + 4 * c) = val;
      }
    }
    // stage Wt: 1024 float4 (4 per thread), contiguous copy
    {
      const float4* srcw = (const float4*)(w1 + (size_t)k0 * CH);
      float4* dstw = (float4*)Wsh;
#pragma unroll
      for (int rep = 0; rep < 4; ++rep) {
        int idx = t + rep * 256;
        dstw[idx] = srcw[idx];
      }
    }
    __syncthreads();
#pragma unroll
    for (int kk = 0; kk < BKK; kk += 4) {
      float4 wq0 = ((const float4*)(Wsh + (kk + 0) * CH))[to];
      float4 wq1 = ((const float4*)(Wsh + (kk + 1) * CH))[to];
      float4 wq2 = ((const float4*)(Wsh + (kk + 2) * CH))[to];
      float4 wq3 = ((const float4*)(Wsh + (kk + 3) * CH))[to];
#pragma unroll
      for (int s8 = 0; s8 < 8; ++s8) {
        float4 a4 = *(const float4*)(Ash + (s8 * 8 + ts) * APAD + kk);
        acc[s8][0] += a4.x * wq0.x; acc[s8][1] += a4.x * wq0.y;
        acc[s8][2] += a4.x * wq0.z; acc[s8][3] += a4.x * wq0.w;
        acc[s8][0] += a4.y * wq1.x; acc[s8][1] += a4.y * wq1.y;
        acc[s8][2] += a4.y * wq1.z; acc[s8][3] += a4.y * wq1.w;
        acc[s8][0] += a4.z * wq2.x; acc[s8][1] += a4.z * wq2.y;
        acc[s8][2] += a4.z * wq2.z; acc[s8][3] += a4.z * wq2.w;
        acc[s8][0] += a4.w * wq3.x; acc[s8][1] += a4.w * wq3.y;
        acc[s8][2] += a4.w * wq3.z; acc[s8][3] += a4.w * wq3.w;
      }
    }
  }

  // head: logp[site][j] = b2[j] + sum_o relu(h[o]) * w2[o][j]
  // thread owns o in {4*to..4*to+3}; butterfly-sum across the 32 'to' lanes.
  float4 w2r0 = *(const float4*)(w2 + (4 * to + 0) * 4);
  float4 w2r1 = *(const float4*)(w2 + (4 * to + 1) * 4);
  float4 w2r2 = *(const float4*)(w2 + (4 * to + 2) * 4);
  float4 w2r3 = *(const float4*)(w2 + (4 * to + 3) * 4);
  float b2v = b2[to & 3];
#pragma unroll
  for (int s8 = 0; s8 < 8; ++s8) {
    float h0 = fmaxf(acc[s8][0], 0.f), h1 = fmaxf(acc[s8][1], 0.f);
    float h2 = fmaxf(acc[s8][2], 0.f), h3 = fmaxf(acc[s8][3], 0.f);
    float pj[4];
    pj[0] = h0 * w2r0.x; pj[0] += h1 * w2r1.x; pj[0] += h2 * w2r2.x; pj[0] += h3 * w2r3.x;
    pj[1] = h0 * w2r0.y; pj[1] += h1 * w2r1.y; pj[1] += h2 * w2r2.y; pj[1] += h3 * w2r3.y;
    pj[2] = h0 * w2r0.z; pj[2] += h1 * w2r1.z; pj[2] += h2 * w2r2.z; pj[2] += h3 * w2r3.z;
    pj[3] = h0 * w2r0.w; pj[3] += h1 * w2r1.w; pj[3] += h2 * w2r2.w; pj[3] += h3 * w2r3.w;
#pragma unroll
    for (int j = 0; j < 4; ++j) {
      float v = pj[j];
      v += __shfl_xor(v, 1);
      v += __shfl_xor(v, 2);
      v += __shfl_xor(v, 4);
      v += __shfl_xor(v, 8);
      v += __shfl_xor(v, 16);
      if (to == s8 * 4 + j) {
        int site = base + s8 * 8 + ts;
        if (site < NNZ) logp[(size_t)site * 4 + j] = v + b2v;
      }
    }
  }
}

// per-query: searchsorted(cum, q, 'right'), gather indices+params, Beta rsample
__global__ __launch_bounds__(256)
void query_kernel(const int* __restrict__ occ_idx,
                  const int* __restrict__ cum,
                  const float* __restrict__ logp,
                  float* __restrict__ out_idx,   // [QMAX, 3] as float
                  float* __restrict__ out_off) { // [QMAX, 2]
  int q = blockIdx.x * 256 + threadIdx.x;
  if (q >= QMAX) return;
  int total = cum[NNZ - 1];
  if (q >= total) {
    out_idx[(size_t)q * 3 + 0] = 0.0f;
    out_idx[(size_t)q * 3 + 1] = 0.0f;
    out_idx[(size_t)q * 3 + 2] = 0.0f;
    out_off[(size_t)q * 2 + 0] = 0.0f;
    out_off[(size_t)q * 2 + 1] = 0.0f;
    return;
  }
  int lo = 0, hi = NNZ;
  while (lo < hi) {
    int mid = (lo + hi) >> 1;
    if (cum[mid] <= q) lo = mid + 1; else hi = mid;
  }
  int src = (lo < NNZ - 1) ? lo : (NNZ - 1);
  out_idx[(size_t)q * 3 + 0] = (float)occ_idx[src];
  out_idx[(size_t)q * 3 + 1] = (float)occ_idx[NNZ + src];
  out_idx[(size_t)q * 3 + 2] = (float)occ_idx[2 * NNZ + src];

  float4 lp = *(const float4*)(logp + (size_t)src * 4);
  float p0 = expf(lp.x), p1 = expf(lp.y), p2 = expf(lp.z), p3 = expf(lp.w);

  Key root{0u, 42u};
  Key k1  = tf_key(root, 0u, 0u);
  Key k2  = tf_key(root, 0u, 1u);
  Key kxa = tf_key(k1, 0u, 0u);
  Key kxb = tf_key(k1, 0u, 1u);
  Key kya = tf_key(k2, 0u, 0u);
  Key kyb = tf_key(k2, 0u, 1u);

  float x = beta_sample(kxa, kxb, (uint32_t)q, p0, p1);
  float y = beta_sample(kya, kyb, (uint32_t)q, p2, p3);
  out_off[(size_t)q * 2 + 0] = x;
  out_off[(size_t)q * 2 + 1] = y;
}

// ============================ launch ============================
extern "C" void kernel_launch(void* const* d_in, const int* in_sizes, int n_in,
                              void* d_out, int out_size, void* d_ws, size_t ws_size,
                              hipStream_t stream) {
  const float* occ_values = (const float*)d_in[0];
  const int*   occ_idx    = (const int*)d_in[1];
  const float* pv         = (const float*)d_in[2];
  const float* w1         = (const float*)d_in[3];
  const float* b1         = (const float*)d_in[4];
  const float* w2         = (const float*)d_in[5];
  const float* b2         = (const float*)d_in[6];

  char* ws = (char*)d_ws;
  auto alignup = [](size_t x) { return (x + 255) & ~(size_t)255; };
  size_t o = 0;
  int* counts  = (int*)(ws + o); o += alignup((size_t)NNZ * 4);
  int* cum     = (int*)(ws + o); o += alignup((size_t)NNZ * 4);
  int* flatall = (int*)(ws + o); o += alignup((size_t)NNZ * 4);
  int* bsums   = (int*)(ws + o); o += alignup(128 * 4);
  float* logp  = (float*)(ws + o); o += alignup((size_t)NNZ * 4 * sizeof(float));

  float* out_idx = (float*)d_out;
  float* out_off = out_idx + (size_t)QMAX * 3;

  counts_kernel<<<(NNZ + 255) / 256, 256, 0, stream>>>(occ_values, occ_idx,
                                                       counts, flatall);
  int nsb = (NNZ + SCAN_B - 1) / SCAN_B;  // 98
  scan_block_kernel<<<nsb, SCAN_B, 0, stream>>>(counts, cum, bsums);
  scan_sums_kernel<<<1, 128, 0, stream>>>(bsums, nsb);
  scan_add_kernel<<<nsb, SCAN_B, 0, stream>>>(cum, bsums);
  conv_head_kernel<<<(NNZ + TSITES - 1) / TSITES, 256, 0, stream>>>(
      occ_idx, flatall, pv, w1, b1, w2, b2, logp);
  query_kernel<<<(QMAX + 255) / 256, 256, 0, stream>>>(occ_idx, cum, logp,
                                                       out_idx, out_off);
}

// Round 4
// 716.760 us; speedup vs baseline: 1.6668x; 1.1025x over previous
//
#include <hip/hip_runtime.h>
#include <cstdint>

#define NNZ   100000
#define CBINS 16
#define HD    1024
#define WD    1024
#define CIN   128
#define CH    128
#define QMAX  (NNZ * (CBINS - 1))

// ============================ threefry2x32 (JAX) ============================
struct Key { uint32_t a, b; };

__device__ __forceinline__ uint32_t rotl32(uint32_t v, int r) {
  return (v << r) | (v >> (32 - r));
}

__device__ __forceinline__ void tf_block(uint32_t k0, uint32_t k1,
                                         uint32_t x0, uint32_t x1,
                                         uint32_t& o0, uint32_t& o1) {
  uint32_t ks2 = k0 ^ k1 ^ 0x1BD11BDAu;
  x0 += k0; x1 += k1;
#define TF_RND(r) { x0 += x1; x1 = rotl32(x1, r); x1 ^= x0; }
  TF_RND(13) TF_RND(15) TF_RND(26) TF_RND(6)
  x0 += k1;  x1 += ks2 + 1u;
  TF_RND(17) TF_RND(29) TF_RND(16) TF_RND(24)
  x0 += ks2; x1 += k0 + 2u;
  TF_RND(13) TF_RND(15) TF_RND(26) TF_RND(6)
  x0 += k0;  x1 += k1 + 3u;
  TF_RND(17) TF_RND(29) TF_RND(16) TF_RND(24)
  x0 += k1;  x1 += ks2 + 4u;
  TF_RND(13) TF_RND(15) TF_RND(26) TF_RND(6)
  x0 += ks2; x1 += k0 + 5u;
#undef TF_RND
  o0 = x0; o1 = x1;
}

__device__ __forceinline__ Key tf_key(Key k, uint32_t chi, uint32_t clo) {
  Key r; tf_block(k.a, k.b, chi, clo, r.a, r.b); return r;
}

__device__ __forceinline__ uint32_t random_bits32(Key k) {
  uint32_t a, b; tf_block(k.a, k.b, 0u, 0u, a, b); return a ^ b;
}

// ============================ JAX float samplers ============================
__device__ __forceinline__ float bits_to_u01(uint32_t bits) {
  uint32_t fb = (bits >> 9) | 0x3F800000u;
  return __uint_as_float(fb) - 1.0f;
}

__device__ float erfinv32(float x) {
#pragma clang fp contract(off)
  float w = -log1pf(-(x * x));
  float p;
  if (w < 5.0f) {
    w = w - 2.5f;
    p = 2.81022636e-08f;
    p = 3.43273939e-07f  + p * w;
    p = -3.5233877e-06f  + p * w;
    p = -4.39150654e-06f + p * w;
    p = 0.00021858087f   + p * w;
    p = -0.00125372503f  + p * w;
    p = -0.00417768164f  + p * w;
    p = 0.246640727f     + p * w;
    p = 1.50140941f      + p * w;
  } else {
    w = sqrtf(w) - 3.0f;
    p = -0.000200214257f;
    p = 0.000100950558f  + p * w;
    p = 0.00134934322f   + p * w;
    p = -0.00367342844f  + p * w;
    p = 0.00573950773f   + p * w;
    p = -0.0076224613f   + p * w;
    p = 0.00943887047f   + p * w;
    p = 1.00167406f      + p * w;
    p = 2.83297682f      + p * w;
  }
  return p * x;
}

__device__ __forceinline__ float uniform01(Key k) {
  return bits_to_u01(random_bits32(k));
}

__device__ __forceinline__ float normal_f32(Key k) {
#pragma clang fp contract(off)
  const float LO = -0x1.fffffep-1f;  // nextafter(-1, 0)
  float f = bits_to_u01(random_bits32(k));
  float u = f * 2.0f + LO;
  u = fmaxf(LO, u);
  return 1.4142135623730951f * erfinv32(u);
}

// _gamma_one(key, alpha, log_space=True) — Marsaglia–Tsang, JAX trace order
__device__ float loggamma_one(Key key, float alpha_orig) {
#pragma clang fp contract(off)
  bool boost = (alpha_orig >= 1.0f);
  float alpha = boost ? alpha_orig : (alpha_orig + 1.0f);
  const float OT = 0.3333333333333333f;
  float d = alpha - OT;
  float c = OT / sqrtf(d);

  Key knext = tf_key(key, 0u, 0u);
  Key ksub  = tf_key(key, 0u, 1u);
  float u_boost = uniform01(ksub);

  float X = 0.0f, V = 1.0f, U = 2.0f;
  while (true) {
    bool c1 = U >= (1.0f - 0.0331f * (X * X));
    bool c2 = logf(U) >= (X * 0.5f + d * ((1.0f - V) + logf(V)));
    if (!(c1 && c2)) break;
    Key kcur = knext;
    knext    = tf_key(kcur, 0u, 0u);
    Key xk   = tf_key(kcur, 0u, 1u);
    Key Uk   = tf_key(kcur, 0u, 2u);
    float x = 0.0f, v = -1.0f;
    while (v <= 0.0f) {
      Key nxk = tf_key(xk, 0u, 0u);
      Key sk  = tf_key(xk, 0u, 1u);
      xk = nxk;
      x = normal_f32(sk);
      v = 1.0f + x * c;
    }
    X = x * x;
    V = (v * v) * v;
    U = uniform01(Uk);
  }
  float log_samples = logf(d) + logf(V);
  float log_boost = 0.0f;
  if (!boost && u_boost != 0.0f)
    log_boost = logf(u_boost) * (1.0f / alpha_orig);
  return log_samples + log_boost;
}

__device__ float beta_sample(Key ka, Key kb, uint32_t q, float a, float b) {
#pragma clang fp contract(off)
  Key ga = tf_key(ka, 0u, q);
  Key gb = tf_key(kb, 0u, q);
  float la = loggamma_one(ga, a);
  float lb = loggamma_one(gb, b);
  float lm = fmaxf(la, lb);
  float ea = expf(la - lm);
  float eb = expf(lb - lm);
  return ea / (ea + eb);
}

// ============================ pipeline kernels ============================

// Exact replica of jax.lax.associative_scan's add association for n=16.
__device__ __forceinline__ void ascan16(const float* a, float* out) {
  float r[8], r2[4], r3[2];
#pragma unroll
  for (int i = 0; i < 8; ++i) r[i] = a[2 * i] + a[2 * i + 1];
#pragma unroll
  for (int i = 0; i < 4; ++i) r2[i] = r[2 * i] + r[2 * i + 1];
  r3[0] = r2[0] + r2[1];
  r3[1] = r2[2] + r2[3];
  float r4 = r3[0] + r3[1];
  float s3[2] = {r3[0], r4};
  float s2[4] = {r2[0], s3[0], s3[0] + r2[2], s3[1]};
  float sr[8] = {r[0],          s2[0],
                 s2[0] + r[2],  s2[1],
                 s2[1] + r[4],  s2[2],
                 s2[2] + r[6],  s2[3]};
  out[0] = a[0];
#pragma unroll
  for (int i = 0; i < 8; ++i) out[2 * i + 1] = sr[i];
#pragma unroll
  for (int i = 0; i < 7; ++i) out[2 * i + 2] = sr[i] + a[2 * i + 2];
}

__global__ __launch_bounds__(256)
void counts_kernel(const float* __restrict__ occ_values,
                   const int* __restrict__ occ_idx,
                   int* __restrict__ counts,
                   int* __restrict__ flatall) {
  int i = blockIdx.x * 256 + threadIdx.x;
  if (i >= NNZ) return;
  const float4* vp = (const float4*)(occ_values + (size_t)i * CBINS);
  float4 q0 = vp[0], q1 = vp[1], q2 = vp[2], q3 = vp[3];
  float v[16] = {q0.x,q0.y,q0.z,q0.w, q1.x,q1.y,q1.z,q1.w,
                 q2.x,q2.y,q2.z,q2.w, q3.x,q3.y,q3.z,q3.w};
  float m = v[0];
#pragma unroll
  for (int k = 1; k < 16; ++k) m = fmaxf(m, v[k]);
  float e[16];
#pragma unroll
  for (int k = 0; k < 16; ++k) e[k] = expf(v[k] - m);
  float s = 0.0f;
#pragma unroll
  for (int k = 0; k < 16; ++k) s += e[k];
  float p[16], cdf[16];
#pragma unroll
  for (int k = 0; k < 16; ++k) p[k] = e[k] / s;
  ascan16(p, cdf);
  int cnt = 0; bool found = false;
#pragma unroll
  for (int k = 0; k < 16; ++k) {
    if (!found && cdf[k] > 0.95f) { found = true; cnt = k; }
  }
  counts[i] = found ? cnt : 0;
  int b_ = occ_idx[i], i_ = occ_idx[NNZ + i], j_ = occ_idx[2 * NNZ + i];
  flatall[i] = (b_ * HD + i_) * WD + j_;
}

#define SCAN_B 1024
__global__ __launch_bounds__(SCAN_B)
void scan_block_kernel(const int* __restrict__ counts, int* __restrict__ cum,
                       int* __restrict__ bsums) {
  __shared__ int sh[SCAN_B];
  int t = threadIdx.x;
  int i = blockIdx.x * SCAN_B + t;
  sh[t] = (i < NNZ) ? counts[i] : 0;
  __syncthreads();
  for (int off = 1; off < SCAN_B; off <<= 1) {
    int add = (t >= off) ? sh[t - off] : 0;
    __syncthreads();
    sh[t] += add;
    __syncthreads();
  }
  if (i < NNZ) cum[i] = sh[t];
  if (t == SCAN_B - 1) bsums[blockIdx.x] = sh[t];
}

__global__ void scan_sums_kernel(int* bsums, int nblocks) {
  __shared__ int sh[128];
  int t = threadIdx.x;
  sh[t] = (t < nblocks) ? bsums[t] : 0;
  __syncthreads();
  for (int off = 1; off < 128; off <<= 1) {
    int add = (t >= off) ? sh[t - off] : 0;
    __syncthreads();
    sh[t] += add;
    __syncthreads();
  }
  if (t < nblocks) bsums[t] = sh[t];
}

__global__ __launch_bounds__(SCAN_B)
void scan_add_kernel(int* cum, const int* __restrict__ bsums) {
  int b = blockIdx.x;
  if (b == 0) return;
  int i = b * SCAN_B + threadIdx.x;
  if (i < NNZ) cum[i] += bsums[b - 1];
}

__device__ __forceinline__ int find_site(const int* __restrict__ flatall, int tval) {
  int lo = 0, hi = NNZ;
  while (lo < hi) {
    int mid = (lo + hi) >> 1;
    if (flatall[mid] < tval) lo = mid + 1; else hi = mid;
  }
  return (lo < NNZ && flatall[lo] == tval) ? lo : -1;
}

// Per-site off-center neighbor rows, in tap order (tap = m<4 ? m : m+1).
__global__ __launch_bounds__(256)
void neighbors_kernel(const int* __restrict__ occ_idx,
                      const int* __restrict__ flatall,
                      int* __restrict__ rlist) {
  int s = blockIdx.x * 256 + threadIdx.x;
  if (s >= NNZ) return;
  int b_ = occ_idx[s], i_ = occ_idx[NNZ + s], j_ = occ_idx[2 * NNZ + s];
  int m = 0;
#pragma unroll
  for (int di = -1; di <= 1; ++di) {
#pragma unroll
    for (int dj = -1; dj <= 1; ++dj) {
      if (di == 0 && dj == 0) continue;
      int ni = i_ + di, nj = j_ + dj, r = -1;
      if ((unsigned)ni < HD && (unsigned)nj < WD)
        r = find_site(flatall, (b_ * HD + ni) * WD + nj);
      rlist[(size_t)s * 8 + m] = r;
      ++m;
    }
  }
}

// Expand ragged repeat: srcmap[q] = owning site for q in [cum[s]-counts[s], cum[s])
__global__ __launch_bounds__(256)
void scatter_src_kernel(const int* __restrict__ counts,
                        const int* __restrict__ cum,
                        int* __restrict__ srcmap) {
  int s = blockIdx.x * 256 + threadIdx.x;
  if (s >= NNZ) return;
  int e = cum[s], c = counts[s];
  for (int q = e - c; q < e; ++q) srcmap[q] = s;
}

// Fused sparse conv: phase 1 = dense center-tap GEMM (h0 tile in LDS),
// phase 2 = per-wave sparse off-center corrections + ReLU + w2 head.
// Deterministic accumulation: center first, then taps ascending.
#define TSITES 64
__global__ __launch_bounds__(256, 4)
void conv_fused_kernel(const float* __restrict__ pv,
                       const float* __restrict__ w1,
                       const float* __restrict__ b1,
                       const float* __restrict__ w2,
                       const float* __restrict__ b2,
                       const int* __restrict__ rlist,
                       float* __restrict__ logp) {
  // smem: Wsh (first 4096 floats) during phase 1; h0[64][128] after.
  __shared__ float smem[TSITES * CH];   // 32 KB
  float* Wsh = smem;
  float* h0  = smem;

  int base = blockIdx.x * TSITES;
  int t = threadIdx.x;
  int ts = t >> 5, to = t & 31;  // thread tile: 8 sites (s8*8+ts) x 4 cols

  float acc[8][4];
  {
    float4 bv = *(const float4*)(b1 + to * 4);
#pragma unroll
    for (int s8 = 0; s8 < 8; ++s8) {
      acc[s8][0] = bv.x; acc[s8][1] = bv.y; acc[s8][2] = bv.z; acc[s8][3] = bv.w;
    }
  }

  // per-thread site rows (clamped for tail block)
  const float* prow[8];
#pragma unroll
  for (int s8 = 0; s8 < 8; ++s8) {
    int site = base + s8 * 8 + ts;
    if (site > NNZ - 1) site = NNZ - 1;
    prow[s8] = pv + (size_t)site * CIN;
  }

  const float* wc = w1 + 4 * CIN * CH;  // center tap
  for (int k0 = 0; k0 < CIN; k0 += 32) {
    __syncthreads();  // WAR on Wsh
    {
      const float4* srcw = (const float4*)(wc + (size_t)k0 * CH);
      float4* dstw = (float4*)Wsh;
#pragma unroll
      for (int rep = 0; rep < 4; ++rep) dstw[t + rep * 256] = srcw[t + rep * 256];
    }
    __syncthreads();
#pragma unroll
    for (int kk = 0; kk < 32; kk += 4) {
      float4 wq0 = ((const float4*)(Wsh + (kk + 0) * CH))[to];
      float4 wq1 = ((const float4*)(Wsh + (kk + 1) * CH))[to];
      float4 wq2 = ((const float4*)(Wsh + (kk + 2) * CH))[to];
      float4 wq3 = ((const float4*)(Wsh + (kk + 3) * CH))[to];
#pragma unroll
      for (int s8 = 0; s8 < 8; ++s8) {
        float4 a4 = *(const float4*)(prow[s8] + k0 + kk);
        acc[s8][0] += a4.x * wq0.x; acc[s8][1] += a4.x * wq0.y;
        acc[s8][2] += a4.x * wq0.z; acc[s8][3] += a4.x * wq0.w;
        acc[s8][0] += a4.y * wq1.x; acc[s8][1] += a4.y * wq1.y;
        acc[s8][2] += a4.y * wq1.z; acc[s8][3] += a4.y * wq1.w;
        acc[s8][0] += a4.z * wq2.x; acc[s8][1] += a4.z * wq2.y;
        acc[s8][2] += a4.z * wq2.z; acc[s8][3] += a4.z * wq2.w;
        acc[s8][0] += a4.w * wq3.x; acc[s8][1] += a4.w * wq3.y;
        acc[s8][2] += a4.w * wq3.z; acc[s8][3] += a4.w * wq3.w;
      }
    }
  }

  __syncthreads();  // all Wsh reads done before h0 overwrites it
#pragma unroll
  for (int s8 = 0; s8 < 8; ++s8) {
    *(float4*)(h0 + (s8 * 8 + ts) * CH + 4 * to) =
        make_float4(acc[s8][0], acc[s8][1], acc[s8][2], acc[s8][3]);
  }
  __syncthreads();

  // phase 2: wave w handles sites base+16w .. base+16w+15
  int w = t >> 6, l = t & 63;
  for (int si = 0; si < 16; ++si) {
    int s = w * 16 + si;
    int site = base + s;
    if (site >= NNZ) break;  // wave-uniform
    float2 hv = *(const float2*)(h0 + s * CH + 2 * l);
    float ha = hv.x, hb = hv.y;
#pragma unroll
    for (int m = 0; m < 8; ++m) {
      int r = rlist[(size_t)site * 8 + m];  // wave-uniform broadcast load
      if (r < 0) continue;                  // wave-uniform skip
      int tap = (m < 4) ? m : m + 1;
      const float* wt = w1 + (size_t)tap * CIN * CH + 2 * l;
      const float* pr = pv + (size_t)r * CIN;
#pragma unroll 8
      for (int k = 0; k < CIN; k += 4) {
        float4 pq = *(const float4*)(pr + k);
        float2 wv0 = *(const float2*)(wt + (k + 0) * CH);
        float2 wv1 = *(const float2*)(wt + (k + 1) * CH);
        float2 wv2 = *(const float2*)(wt + (k + 2) * CH);
        float2 wv3 = *(const float2*)(wt + (k + 3) * CH);
        ha += pq.x * wv0.x; hb += pq.x * wv0.y;
        ha += pq.y * wv1.x; hb += pq.y * wv1.y;
        ha += pq.z * wv2.x; hb += pq.z * wv2.y;
        ha += pq.w * wv3.x; hb += pq.w * wv3.y;
      }
    }
    // head: logp[site][j] = b2[j] + sum_o relu(h[o]) * w2[o][j]
    float r0 = fmaxf(ha, 0.f), r1 = fmaxf(hb, 0.f);
    float4 wa = *(const float4*)(w2 + (2 * l + 0) * 4);
    float4 wb = *(const float4*)(w2 + (2 * l + 1) * 4);
    float pj0 = r0 * wa.x; pj0 += r1 * wb.x;
    float pj1 = r0 * wa.y; pj1 += r1 * wb.y;
    float pj2 = r0 * wa.z; pj2 += r1 * wb.z;
    float pj3 = r0 * wa.w; pj3 += r1 * wb.w;
#pragma unroll
    for (int st = 1; st < 64; st <<= 1) {
      pj0 += __shfl_xor(pj0, st);
      pj1 += __shfl_xor(pj1, st);
      pj2 += __shfl_xor(pj2, st);
      pj3 += __shfl_xor(pj3, st);
    }
    if (l < 4) {
      float pj = (l == 0) ? pj0 : (l == 1) ? pj1 : (l == 2) ? pj2 : pj3;
      logp[(size_t)site * 4 + l] = pj + b2[l];
    }
  }
}

// per-query: srcmap lookup, gather indices+params, Beta rsample
__global__ __launch_bounds__(256)
void query_kernel(const int* __restrict__ occ_idx,
                  const int* __restrict__ cum,
                  const int* __restrict__ srcmap,
                  const float* __restrict__ logp,
                  float* __restrict__ out_idx,   // [QMAX, 3] as float
                  float* __restrict__ out_off) { // [QMAX, 2]
  int q = blockIdx.x * 256 + threadIdx.x;
  if (q >= QMAX) return;
  int total = cum[NNZ - 1];
  if (q >= total) {
    out_idx[(size_t)q * 3 + 0] = 0.0f;
    out_idx[(size_t)q * 3 + 1] = 0.0f;
    out_idx[(size_t)q * 3 + 2] = 0.0f;
    out_off[(size_t)q * 2 + 0] = 0.0f;
    out_off[(size_t)q * 2 + 1] = 0.0f;
    return;
  }
  int src = srcmap[q];
  out_idx[(size_t)q * 3 + 0] = (float)occ_idx[src];
  out_idx[(size_t)q * 3 + 1] = (float)occ_idx[NNZ + src];
  out_idx[(size_t)q * 3 + 2] = (float)occ_idx[2 * NNZ + src];

  float4 lp = *(const float4*)(logp + (size_t)src * 4);
  float p0 = expf(lp.x), p1 = expf(lp.y), p2 = expf(lp.z), p3 = expf(lp.w);

  Key root{0u, 42u};
  Key k1  = tf_key(root, 0u, 0u);
  Key k2  = tf_key(root, 0u, 1u);
  Key kxa = tf_key(k1, 0u, 0u);
  Key kxb = tf_key(k1, 0u, 1u);
  Key kya = tf_key(k2, 0u, 0u);
  Key kyb = tf_key(k2, 0u, 1u);

  float x = beta_sample(kxa, kxb, (uint32_t)q, p0, p1);
  float y = beta_sample(kya, kyb, (uint32_t)q, p2, p3);
  out_off[(size_t)q * 2 + 0] = x;
  out_off[(size_t)q * 2 + 1] = y;
}

// ============================ launch ============================
extern "C" void kernel_launch(void* const* d_in, const int* in_sizes, int n_in,
                              void* d_out, int out_size, void* d_ws, size_t ws_size,
                              hipStream_t stream) {
  const float* occ_values = (const float*)d_in[0];
  const int*   occ_idx    = (const int*)d_in[1];
  const float* pv         = (const float*)d_in[2];
  const float* w1         = (const float*)d_in[3];
  const float* b1         = (const float*)d_in[4];
  const float* w2         = (const float*)d_in[5];
  const float* b2         = (const float*)d_in[6];

  char* ws = (char*)d_ws;
  auto alignup = [](size_t x) { return (x + 255) & ~(size_t)255; };
  size_t o = 0;
  int* counts  = (int*)(ws + o); o += alignup((size_t)NNZ * 4);
  int* cum     = (int*)(ws + o); o += alignup((size_t)NNZ * 4);
  int* flatall = (int*)(ws + o); o += alignup((size_t)NNZ * 4);
  int* bsums   = (int*)(ws + o); o += alignup(128 * 4);
  float* logp  = (float*)(ws + o); o += alignup((size_t)NNZ * 4 * sizeof(float));
  int* rlist   = (int*)(ws + o); o += alignup((size_t)NNZ * 8 * 4);
  int* srcmap  = (int*)(ws + o); o += alignup((size_t)QMAX * 4);

  float* out_idx = (float*)d_out;
  float* out_off = out_idx + (size_t)QMAX * 3;

  counts_kernel<<<(NNZ + 255) / 256, 256, 0, stream>>>(occ_values, occ_idx,
                                                       counts, flatall);
  int nsb = (NNZ + SCAN_B - 1) / SCAN_B;  // 98
  scan_block_kernel<<<nsb, SCAN_B, 0, stream>>>(counts, cum, bsums);
  scan_sums_kernel<<<1, 128, 0, stream>>>(bsums, nsb);
  scan_add_kernel<<<nsb, SCAN_B, 0, stream>>>(cum, bsums);
  neighbors_kernel<<<(NNZ + 255) / 256, 256, 0, stream>>>(occ_idx, flatall, rlist);
  scatter_src_kernel<<<(NNZ + 255) / 256, 256, 0, stream>>>(counts, cum, srcmap);
  conv_fused_kernel<<<(NNZ + TSITES - 1) / TSITES, 256, 0, stream>>>(
      pv, w1, b1, w2, b2, rlist, logp);
  query_kernel<<<(QMAX + 255) / 256, 256, 0, stream>>>(occ_idx, cum, srcmap,
                                                       logp, out_idx, out_off);
}

// Round 5
// 715.204 us; speedup vs baseline: 1.6705x; 1.0022x over previous
//
#include <hip/hip_runtime.h>
#include <cstdint>

#define NNZ   100000
#define CBINS 16
#define HD    1024
#define WD    1024
#define CIN   128
#define CH    128
#define QMAX  (NNZ * (CBINS - 1))

// ============================ threefry2x32 (JAX) ============================
struct Key { uint32_t a, b; };

__device__ __forceinline__ uint32_t rotl32(uint32_t v, int r) {
  return (v << r) | (v >> (32 - r));
}

__device__ __forceinline__ void tf_block(uint32_t k0, uint32_t k1,
                                         uint32_t x0, uint32_t x1,
                                         uint32_t& o0, uint32_t& o1) {
  uint32_t ks2 = k0 ^ k1 ^ 0x1BD11BDAu;
  x0 += k0; x1 += k1;
#define TF_RND(r) { x0 += x1; x1 = rotl32(x1, r); x1 ^= x0; }
  TF_RND(13) TF_RND(15) TF_RND(26) TF_RND(6)
  x0 += k1;  x1 += ks2 + 1u;
  TF_RND(17) TF_RND(29) TF_RND(16) TF_RND(24)
  x0 += ks2; x1 += k0 + 2u;
  TF_RND(13) TF_RND(15) TF_RND(26) TF_RND(6)
  x0 += k0;  x1 += k1 + 3u;
  TF_RND(17) TF_RND(29) TF_RND(16) TF_RND(24)
  x0 += k1;  x1 += ks2 + 4u;
  TF_RND(13) TF_RND(15) TF_RND(26) TF_RND(6)
  x0 += ks2; x1 += k0 + 5u;
#undef TF_RND
  o0 = x0; o1 = x1;
}

__device__ __forceinline__ Key tf_key(Key k, uint32_t chi, uint32_t clo) {
  Key r; tf_block(k.a, k.b, chi, clo, r.a, r.b); return r;
}

__device__ __forceinline__ uint32_t random_bits32(Key k) {
  uint32_t a, b; tf_block(k.a, k.b, 0u, 0u, a, b); return a ^ b;
}

// ============================ JAX float samplers ============================
__device__ __forceinline__ float bits_to_u01(uint32_t bits) {
  uint32_t fb = (bits >> 9) | 0x3F800000u;
  return __uint_as_float(fb) - 1.0f;
}

__device__ float erfinv32(float x) {
#pragma clang fp contract(off)
  float w = -log1pf(-(x * x));
  float p;
  if (w < 5.0f) {
    w = w - 2.5f;
    p = 2.81022636e-08f;
    p = 3.43273939e-07f  + p * w;
    p = -3.5233877e-06f  + p * w;
    p = -4.39150654e-06f + p * w;
    p = 0.00021858087f   + p * w;
    p = -0.00125372503f  + p * w;
    p = -0.00417768164f  + p * w;
    p = 0.246640727f     + p * w;
    p = 1.50140941f      + p * w;
  } else {
    w = sqrtf(w) - 3.0f;
    p = -0.000200214257f;
    p = 0.000100950558f  + p * w;
    p = 0.00134934322f   + p * w;
    p = -0.00367342844f  + p * w;
    p = 0.00573950773f   + p * w;
    p = -0.0076224613f   + p * w;
    p = 0.00943887047f   + p * w;
    p = 1.00167406f      + p * w;
    p = 2.83297682f      + p * w;
  }
  return p * x;
}

__device__ __forceinline__ float uniform01(Key k) {
  return bits_to_u01(random_bits32(k));
}

__device__ __forceinline__ float normal_f32(Key k) {
#pragma clang fp contract(off)
  const float LO = -0x1.fffffep-1f;  // nextafter(-1, 0)
  float f = bits_to_u01(random_bits32(k));
  float u = f * 2.0f + LO;
  u = fmaxf(LO, u);
  return 1.4142135623730951f * erfinv32(u);
}

// _gamma_one(key, alpha, log_space=True) — Marsaglia–Tsang, JAX trace order
__device__ float loggamma_one(Key key, float alpha_orig) {
#pragma clang fp contract(off)
  bool boost = (alpha_orig >= 1.0f);
  float alpha = boost ? alpha_orig : (alpha_orig + 1.0f);
  const float OT = 0.3333333333333333f;
  float d = alpha - OT;
  float c = OT / sqrtf(d);

  Key knext = tf_key(key, 0u, 0u);
  Key ksub  = tf_key(key, 0u, 1u);
  float u_boost = uniform01(ksub);

  float X = 0.0f, V = 1.0f, U = 2.0f;
  while (true) {
    bool c1 = U >= (1.0f - 0.0331f * (X * X));
    bool c2 = logf(U) >= (X * 0.5f + d * ((1.0f - V) + logf(V)));
    if (!(c1 && c2)) break;
    Key kcur = knext;
    knext    = tf_key(kcur, 0u, 0u);
    Key xk   = tf_key(kcur, 0u, 1u);
    Key Uk   = tf_key(kcur, 0u, 2u);
    float x = 0.0f, v = -1.0f;
    while (v <= 0.0f) {
      Key nxk = tf_key(xk, 0u, 0u);
      Key sk  = tf_key(xk, 0u, 1u);
      xk = nxk;
      x = normal_f32(sk);
      v = 1.0f + x * c;
    }
    X = x * x;
    V = (v * v) * v;
    U = uniform01(Uk);
  }
  float log_samples = logf(d) + logf(V);
  float log_boost = 0.0f;
  if (!boost && u_boost != 0.0f)
    log_boost = logf(u_boost) * (1.0f / alpha_orig);
  return log_samples + log_boost;
}

__device__ float beta_sample(Key ka, Key kb, uint32_t q, float a, float b) {
#pragma clang fp contract(off)
  Key ga = tf_key(ka, 0u, q);
  Key gb = tf_key(kb, 0u, q);
  float la = loggamma_one(ga, a);
  float lb = loggamma_one(gb, b);
  float lm = fmaxf(la, lb);
  float ea = expf(la - lm);
  float eb = expf(lb - lm);
  return ea / (ea + eb);
}

// ============================ pipeline kernels ============================

// Exact replica of jax.lax.associative_scan's add association for n=16.
__device__ __forceinline__ void ascan16(const float* a, float* out) {
  float r[8], r2[4], r3[2];
#pragma unroll
  for (int i = 0; i < 8; ++i) r[i] = a[2 * i] + a[2 * i + 1];
#pragma unroll
  for (int i = 0; i < 4; ++i) r2[i] = r[2 * i] + r[2 * i + 1];
  r3[0] = r2[0] + r2[1];
  r3[1] = r2[2] + r2[3];
  float r4 = r3[0] + r3[1];
  float s3[2] = {r3[0], r4};
  float s2[4] = {r2[0], s3[0], s3[0] + r2[2], s3[1]};
  float sr[8] = {r[0],          s2[0],
                 s2[0] + r[2],  s2[1],
                 s2[1] + r[4],  s2[2],
                 s2[2] + r[6],  s2[3]};
  out[0] = a[0];
#pragma unroll
  for (int i = 0; i < 8; ++i) out[2 * i + 1] = sr[i];
#pragma unroll
  for (int i = 0; i < 7; ++i) out[2 * i + 2] = sr[i] + a[2 * i + 2];
}

__global__ __launch_bounds__(256)
void counts_kernel(const float* __restrict__ occ_values,
                   const int* __restrict__ occ_idx,
                   int* __restrict__ counts,
                   int* __restrict__ flatall) {
  int i = blockIdx.x * 256 + threadIdx.x;
  if (i >= NNZ) return;
  const float4* vp = (const float4*)(occ_values + (size_t)i * CBINS);
  float4 q0 = vp[0], q1 = vp[1], q2 = vp[2], q3 = vp[3];
  float v[16] = {q0.x,q0.y,q0.z,q0.w, q1.x,q1.y,q1.z,q1.w,
                 q2.x,q2.y,q2.z,q2.w, q3.x,q3.y,q3.z,q3.w};
  float m = v[0];
#pragma unroll
  for (int k = 1; k < 16; ++k) m = fmaxf(m, v[k]);
  float e[16];
#pragma unroll
  for (int k = 0; k < 16; ++k) e[k] = expf(v[k] - m);
  float s = 0.0f;
#pragma unroll
  for (int k = 0; k < 16; ++k) s += e[k];
  float p[16], cdf[16];
#pragma unroll
  for (int k = 0; k < 16; ++k) p[k] = e[k] / s;
  ascan16(p, cdf);
  int cnt = 0; bool found = false;
#pragma unroll
  for (int k = 0; k < 16; ++k) {
    if (!found && cdf[k] > 0.95f) { found = true; cnt = k; }
  }
  counts[i] = found ? cnt : 0;
  int b_ = occ_idx[i], i_ = occ_idx[NNZ + i], j_ = occ_idx[2 * NNZ + i];
  flatall[i] = (b_ * HD + i_) * WD + j_;
}

#define SCAN_B 1024
__global__ __launch_bounds__(SCAN_B)
void scan_block_kernel(const int* __restrict__ counts, int* __restrict__ cum,
                       int* __restrict__ bsums) {
  __shared__ int sh[SCAN_B];
  int t = threadIdx.x;
  int i = blockIdx.x * SCAN_B + t;
  sh[t] = (i < NNZ) ? counts[i] : 0;
  __syncthreads();
  for (int off = 1; off < SCAN_B; off <<= 1) {
    int add = (t >= off) ? sh[t - off] : 0;
    __syncthreads();
    sh[t] += add;
    __syncthreads();
  }
  if (i < NNZ) cum[i] = sh[t];
  if (t == SCAN_B - 1) bsums[blockIdx.x] = sh[t];
}

__global__ void scan_sums_kernel(int* bsums, int nblocks) {
  __shared__ int sh[128];
  int t = threadIdx.x;
  sh[t] = (t < nblocks) ? bsums[t] : 0;
  __syncthreads();
  for (int off = 1; off < 128; off <<= 1) {
    int add = (t >= off) ? sh[t - off] : 0;
    __syncthreads();
    sh[t] += add;
    __syncthreads();
  }
  if (t < nblocks) bsums[t] = sh[t];
}

__global__ __launch_bounds__(SCAN_B)
void scan_add_kernel(int* cum, const int* __restrict__ bsums) {
  int b = blockIdx.x;
  if (b == 0) return;
  int i = b * SCAN_B + threadIdx.x;
  if (i < NNZ) cum[i] += bsums[b - 1];
}

__device__ __forceinline__ int find_site(const int* __restrict__ flatall, int tval) {
  int lo = 0, hi = NNZ;
  while (lo < hi) {
    int mid = (lo + hi) >> 1;
    if (flatall[mid] < tval) lo = mid + 1; else hi = mid;
  }
  return (lo < NNZ && flatall[lo] == tval) ? lo : -1;
}

// Per-site off-center neighbor rows, in tap order (tap = m<4 ? m : m+1).
__global__ __launch_bounds__(256)
void neighbors_kernel(const int* __restrict__ occ_idx,
                      const int* __restrict__ flatall,
                      int* __restrict__ rlist) {
  int s = blockIdx.x * 256 + threadIdx.x;
  if (s >= NNZ) return;
  int b_ = occ_idx[s], i_ = occ_idx[NNZ + s], j_ = occ_idx[2 * NNZ + s];
  int m = 0;
#pragma unroll
  for (int di = -1; di <= 1; ++di) {
#pragma unroll
    for (int dj = -1; dj <= 1; ++dj) {
      if (di == 0 && dj == 0) continue;
      int ni = i_ + di, nj = j_ + dj, r = -1;
      if ((unsigned)ni < HD && (unsigned)nj < WD)
        r = find_site(flatall, (b_ * HD + ni) * WD + nj);
      rlist[(size_t)s * 8 + m] = r;
      ++m;
    }
  }
}

// Expand ragged repeat: srcmap[q] = owning site for q in [cum[s]-counts[s], cum[s])
__global__ __launch_bounds__(256)
void scatter_src_kernel(const int* __restrict__ counts,
                        const int* __restrict__ cum,
                        int* __restrict__ srcmap) {
  int s = blockIdx.x * 256 + threadIdx.x;
  if (s >= NNZ) return;
  int e = cum[s], c = counts[s];
  for (int q = e - c; q < e; ++q) srcmap[q] = s;
}

// Fused sparse conv: phase 1 = dense center-tap GEMM, phase 2 = sparse
// off-center corrections (rlist prefetched to LDS), phase 3 = w2 head from
// the LDS h-tile. Deterministic accumulation: center, then taps ascending.
#define TSITES 64
#define HP     132   // h0 row pad: 16B-aligned rows, 4 mod 32 banks
__global__ __launch_bounds__(256, 4)
void conv_fused_kernel(const float* __restrict__ pv,
                       const float* __restrict__ w1,
                       const float* __restrict__ b1,
                       const float* __restrict__ w2,
                       const float* __restrict__ b2,
                       const int* __restrict__ rlist,
                       float* __restrict__ logp) {
  __shared__ float smem[TSITES * HP];   // 33 KB: Wsh during phase 1, h0 after
  __shared__ int rl[TSITES * 8];        // 2 KB: prefetched neighbor rows
  float* Wsh = smem;
  float* h0  = smem;

  int base = blockIdx.x * TSITES;
  int t = threadIdx.x;

  // prefetch rlist for all 64 sites (2 loads/thread); latency hides behind
  // phase 1's GEMM. Tail block: clamp site (entries never read past NNZ).
#pragma unroll
  for (int rep = 0; rep < 2; ++rep) {
    int e = t + rep * 256;
    int sc = base + (e >> 3);
    if (sc > NNZ - 1) sc = NNZ - 1;
    rl[e] = rlist[(size_t)sc * 8 + (e & 7)];
  }

  int ts = t >> 5, to = t & 31;  // thread tile: 8 sites (s8*8+ts) x 4 cols
  float acc[8][4];
  {
    float4 bv = *(const float4*)(b1 + to * 4);
#pragma unroll
    for (int s8 = 0; s8 < 8; ++s8) {
      acc[s8][0] = bv.x; acc[s8][1] = bv.y; acc[s8][2] = bv.z; acc[s8][3] = bv.w;
    }
  }

  const float* prow[8];
#pragma unroll
  for (int s8 = 0; s8 < 8; ++s8) {
    int site = base + s8 * 8 + ts;
    if (site > NNZ - 1) site = NNZ - 1;
    prow[s8] = pv + (size_t)site * CIN;
  }

  const float* wc = w1 + 4 * CIN * CH;  // center tap
  for (int k0 = 0; k0 < CIN; k0 += 32) {
    __syncthreads();  // WAR on Wsh
    {
      const float4* srcw = (const float4*)(wc + (size_t)k0 * CH);
      float4* dstw = (float4*)Wsh;
#pragma unroll
      for (int rep = 0; rep < 4; ++rep) dstw[t + rep * 256] = srcw[t + rep * 256];
    }
    __syncthreads();
#pragma unroll
    for (int kk = 0; kk < 32; kk += 4) {
      float4 wq0 = ((const float4*)(Wsh + (kk + 0) * CH))[to];
      float4 wq1 = ((const float4*)(Wsh + (kk + 1) * CH))[to];
      float4 wq2 = ((const float4*)(Wsh + (kk + 2) * CH))[to];
      float4 wq3 = ((const float4*)(Wsh + (kk + 3) * CH))[to];
#pragma unroll
      for (int s8 = 0; s8 < 8; ++s8) {
        float4 a4 = *(const float4*)(prow[s8] + k0 + kk);
        acc[s8][0] += a4.x * wq0.x; acc[s8][1] += a4.x * wq0.y;
        acc[s8][2] += a4.x * wq0.z; acc[s8][3] += a4.x * wq0.w;
        acc[s8][0] += a4.y * wq1.x; acc[s8][1] += a4.y * wq1.y;
        acc[s8][2] += a4.y * wq1.z; acc[s8][3] += a4.y * wq1.w;
        acc[s8][0] += a4.z * wq2.x; acc[s8][1] += a4.z * wq2.y;
        acc[s8][2] += a4.z * wq2.z; acc[s8][3] += a4.z * wq2.w;
        acc[s8][0] += a4.w * wq3.x; acc[s8][1] += a4.w * wq3.y;
        acc[s8][2] += a4.w * wq3.z; acc[s8][3] += a4.w * wq3.w;
      }
    }
  }

  __syncthreads();  // Wsh reads done before h0 overwrites it
#pragma unroll
  for (int s8 = 0; s8 < 8; ++s8) {
    *(float4*)(h0 + (s8 * 8 + ts) * HP + 4 * to) =
        make_float4(acc[s8][0], acc[s8][1], acc[s8][2], acc[s8][3]);
  }
  __syncthreads();

  // phase 2: wave w owns sites base+16w..+15; lane l owns h[site][2l..2l+1]
  int w = t >> 6, l = t & 63;
  for (int si = 0; si < 16; ++si) {
    int s = w * 16 + si;
    int site = base + s;
    if (site >= NNZ) break;  // wave-uniform
    float2 hv = *(const float2*)(h0 + s * HP + 2 * l);
    float ha = hv.x, hb = hv.y;
#pragma unroll
    for (int m = 0; m < 8; ++m) {
      int r = rl[s * 8 + m];  // LDS broadcast read
      if (r < 0) continue;    // wave-uniform skip
      int tap = (m < 4) ? m : m + 1;
      const float* wt = w1 + (size_t)tap * CIN * CH + 2 * l;
      const float* pr = pv + (size_t)r * CIN;
#pragma unroll 8
      for (int k = 0; k < CIN; k += 4) {
        float4 pq = *(const float4*)(pr + k);
        float2 wv0 = *(const float2*)(wt + (k + 0) * CH);
        float2 wv1 = *(const float2*)(wt + (k + 1) * CH);
        float2 wv2 = *(const float2*)(wt + (k + 2) * CH);
        float2 wv3 = *(const float2*)(wt + (k + 3) * CH);
        ha += pq.x * wv0.x; hb += pq.x * wv0.y;
        ha += pq.y * wv1.x; hb += pq.y * wv1.y;
        ha += pq.z * wv2.x; hb += pq.z * wv2.y;
        ha += pq.w * wv3.x; hb += pq.w * wv3.y;
      }
    }
    *(float2*)(h0 + s * HP + 2 * l) = make_float2(ha, hb);
  }
  __syncthreads();

  // phase 3: head. thread t -> (site s = t&63, output j = t>>6);
  // serial ascending-o association (matches round-2's passing head).
  {
    int s = t & 63, j = t >> 6;
    int site = base + s;
    if (site < NNZ) {
      const float* hr = h0 + s * HP;
      float sum = 0.0f;
      for (int o = 0; o < CH; o += 2) {
        float2 hv = *(const float2*)(hr + o);
        sum += fmaxf(hv.x, 0.f) * w2[(o + 0) * 4 + j];
        sum += fmaxf(hv.y, 0.f) * w2[(o + 1) * 4 + j];
      }
      logp[(size_t)site * 4 + j] = sum + b2[j];
    }
  }
}

// per-query: srcmap lookup, gather indices+params, Beta rsample
__global__ __launch_bounds__(256)
void query_kernel(const int* __restrict__ occ_idx,
                  const int* __restrict__ cum,
                  const int* __restrict__ srcmap,
                  const float* __restrict__ logp,
                  float* __restrict__ out_idx,   // [QMAX, 3] as float
                  float* __restrict__ out_off) { // [QMAX, 2]
  int q = blockIdx.x * 256 + threadIdx.x;
  if (q >= QMAX) return;
  int total = cum[NNZ - 1];
  if (q >= total) {
    out_idx[(size_t)q * 3 + 0] = 0.0f;
    out_idx[(size_t)q * 3 + 1] = 0.0f;
    out_idx[(size_t)q * 3 + 2] = 0.0f;
    out_off[(size_t)q * 2 + 0] = 0.0f;
    out_off[(size_t)q * 2 + 1] = 0.0f;
    return;
  }
  int src = srcmap[q];
  out_idx[(size_t)q * 3 + 0] = (float)occ_idx[src];
  out_idx[(size_t)q * 3 + 1] = (float)occ_idx[NNZ + src];
  out_idx[(size_t)q * 3 + 2] = (float)occ_idx[2 * NNZ + src];

  float4 lp = *(const float4*)(logp + (size_t)src * 4);
  float p0 = expf(lp.x), p1 = expf(lp.y), p2 = expf(lp.z), p3 = expf(lp.w);

  Key root{0u, 42u};
  Key k1  = tf_key(root, 0u, 0u);
  Key k2  = tf_key(root, 0u, 1u);
  Key kxa = tf_key(k1, 0u, 0u);
  Key kxb = tf_key(k1, 0u, 1u);
  Key kya = tf_key(k2, 0u, 0u);
  Key kyb = tf_key(k2, 0u, 1u);

  float x = beta_sample(kxa, kxb, (uint32_t)q, p0, p1);
  float y = beta_sample(kya, kyb, (uint32_t)q, p2, p3);
  out_off[(size_t)q * 2 + 0] = x;
  out_off[(size_t)q * 2 + 1] = y;
}

// ============================ launch ============================
extern "C" void kernel_launch(void* const* d_in, const int* in_sizes, int n_in,
                              void* d_out, int out_size, void* d_ws, size_t ws_size,
                              hipStream_t stream) {
  const float* occ_values = (const float*)d_in[0];
  const int*   occ_idx    = (const int*)d_in[1];
  const float* pv         = (const float*)d_in[2];
  const float* w1         = (const float*)d_in[3];
  const float* b1         = (const float*)d_in[4];
  const float* w2         = (const float*)d_in[5];
  const float* b2         = (const float*)d_in[6];

  char* ws = (char*)d_ws;
  auto alignup = [](size_t x) { return (x + 255) & ~(size_t)255; };
  size_t o = 0;
  int* counts  = (int*)(ws + o); o += alignup((size_t)NNZ * 4);
  int* cum     = (int*)(ws + o); o += alignup((size_t)NNZ * 4);
  int* flatall = (int*)(ws + o); o += alignup((size_t)NNZ * 4);
  int* bsums   = (int*)(ws + o); o += alignup(128 * 4);
  float* logp  = (float*)(ws + o); o += alignup((size_t)NNZ * 4 * sizeof(float));
  int* rlist   = (int*)(ws + o); o += alignup((size_t)NNZ * 8 * 4);
  int* srcmap  = (int*)(ws + o); o += alignup((size_t)QMAX * 4);

  float* out_idx = (float*)d_out;
  float* out_off = out_idx + (size_t)QMAX * 3;

  counts_kernel<<<(NNZ + 255) / 256, 256, 0, stream>>>(occ_values, occ_idx,
                                                       counts, flatall);
  int nsb = (NNZ + SCAN_B - 1) / SCAN_B;  // 98
  scan_block_kernel<<<nsb, SCAN_B, 0, stream>>>(counts, cum, bsums);
  scan_sums_kernel<<<1, 128, 0, stream>>>(bsums, nsb);
  scan_add_kernel<<<nsb, SCAN_B, 0, stream>>>(cum, bsums);
  neighbors_kernel<<<(NNZ + 255) / 256, 256, 0, stream>>>(occ_idx, flatall, rlist);
  scatter_src_kernel<<<(NNZ + 255) / 256, 256, 0, stream>>>(counts, cum, srcmap);
  conv_fused_kernel<<<(NNZ + TSITES - 1) / TSITES, 256, 0, stream>>>(
      pv, w1, b1, w2, b2, rlist, logp);
  query_kernel<<<(QMAX + 255) / 256, 256, 0, stream>>>(occ_idx, cum, srcmap,
                                                       logp, out_idx, out_off);
}